// Round 2
// baseline (375.653 us; speedup 1.0000x reference)
//
#include <hip/hip_runtime.h>
#include <hip/hip_cooperative_groups.h>
#include <cmath>

namespace cg = cooperative_groups;

#define V 50257
#define H 1024
#define NBLK 1024
#define NTHR 256

// ws layout (floats):
// [0, H)              h1
// [H, H + 2*NBLK)     per-block (max, sumexp) partials

__device__ __forceinline__ float dot4(float4 a, float4 b) {
    return a.x * b.x + a.y * b.y + a.z * b.z + a.w * b.w;
}

// online logsumexp merge: (m,s) <- merge((m,s),(mo,so))
__device__ __forceinline__ void lse_merge(float& m, float& s, float mo, float so) {
    const float mn = fmaxf(m, mo);
    s = s * expf(m - mn) + so * expf(mo - mn);
    m = mn;
}

__global__ __launch_bounds__(NTHR, 4) void k_fused(
    const int* __restrict__ token,
    const float* __restrict__ h0,
    const float* __restrict__ c0,
    const float* __restrict__ emb,
    const float* __restrict__ W_ih,
    const float* __restrict__ W_hh,
    const float* __restrict__ b_ih,
    const float* __restrict__ b_hh,
    const float* __restrict__ W_out,
    const float* __restrict__ b_out,
    float* __restrict__ out,
    float* __restrict__ ws) {
    cg::grid_group grid = cg::this_grid();
    const int tid = threadIdx.x;
    const int wid = tid >> 6, lane = tid & 63;
    const int bid = blockIdx.x;

    float* h1ws     = ws;
    float* partials = ws + H;

    // ---------- Phase 1: gates + LSTM cell. Block j handles hidden unit j. ----------
    {
        const int j = bid;                // 0..1023 == H
        const int tok = token[0];
        const int row = wid * H + j;      // wave 0..3 -> gates i,f,g,o
        const float4* x4 = (const float4*)(emb + (size_t)tok * H);
        const float4* h4 = (const float4*)h0;
        const float4* wi = (const float4*)(W_ih + (size_t)row * H);
        const float4* wh = (const float4*)(W_hh + (size_t)row * H);

        float acc = 0.f;
#pragma unroll
        for (int it = 0; it < 4; ++it) {
            const int k4 = it * 64 + lane;
            float4 xv = x4[k4];
            xv.x = fmaxf(xv.x, 0.f); xv.y = fmaxf(xv.y, 0.f);
            xv.z = fmaxf(xv.z, 0.f); xv.w = fmaxf(xv.w, 0.f);
            acc += dot4(wi[k4], xv);
            acc += dot4(wh[k4], h4[k4]);
        }
#pragma unroll
        for (int off = 32; off; off >>= 1) acc += __shfl_down(acc, off);

        __shared__ float gsh[4];
        if (lane == 0) gsh[wid] = acc + b_ih[row] + b_hh[row];
        __syncthreads();
        if (tid == 0) {
            const float gi = gsh[0], gf = gsh[1], gg = gsh[2], go = gsh[3];
            const float si = 1.f / (1.f + expf(-gi));
            const float sf = 1.f / (1.f + expf(-gf));
            const float so = 1.f / (1.f + expf(-go));
            const float c1 = sf * c0[j] + si * tanhf(gg);
            const float h1 = so * tanhf(c1);
            out[V + j]     = h1;
            out[V + H + j] = c1;
            h1ws[j]        = h1;
        }
    }
    __threadfence();
    grid.sync();

    // ---------- Phase 2: logits + per-block softmax partials ----------
    {
        float4 hv[4];
        const float4* h4w = (const float4*)h1ws;
#pragma unroll
        for (int it = 0; it < 4; ++it) hv[it] = h4w[it * 64 + lane];

        float m = -INFINITY, s = 0.f;  // lane 0 of each wave accumulates
        for (int r = bid + wid * NBLK; r < V; r += 4 * NBLK) {
            const float4* w = (const float4*)(W_out + (size_t)r * H);
            float acc = 0.f;
#pragma unroll
            for (int it = 0; it < 4; ++it) acc += dot4(w[it * 64 + lane], hv[it]);
#pragma unroll
            for (int off = 32; off; off >>= 1) acc += __shfl_down(acc, off);
            if (lane == 0) {
                const float l = acc + b_out[r];
                out[r] = l;
                const float mn = fmaxf(m, l);
                s = s * expf(m - mn) + expf(l - mn);
                m = mn;
            }
        }

        __shared__ float sm[4], ssum[4];
        if (lane == 0) { sm[wid] = m; ssum[wid] = s; }
        __syncthreads();
        if (tid == 0) {
            float M = sm[0], S = ssum[0];
#pragma unroll
            for (int w = 1; w < 4; ++w) lse_merge(M, S, sm[w], ssum[w]);
            partials[2 * bid]     = M;
            partials[2 * bid + 1] = S;
        }
    }
    __threadfence();
    grid.sync();

    // ---------- Phase 3: redundant combine + subtract (first 197 blocks) ----------
    {
        const int NSUB = (V + NTHR - 1) / NTHR;  // 197
        if (bid >= NSUB) return;

        float m = -INFINITY, s = 0.f;
#pragma unroll
        for (int t = 0; t < NBLK / NTHR; ++t) {  // 4 entries per thread
            const int i = t * NTHR + tid;
            lse_merge(m, s, partials[2 * i], partials[2 * i + 1]);
        }
#pragma unroll
        for (int off = 32; off; off >>= 1) {
            const float mo = __shfl_down(m, off), so = __shfl_down(s, off);
            lse_merge(m, s, mo, so);
        }
        __shared__ float cm[4], cs[4], st_sh;
        if (lane == 0) { cm[wid] = m; cs[wid] = s; }
        __syncthreads();
        if (tid == 0) {
            float M = cm[0], S = cs[0];
#pragma unroll
            for (int w = 1; w < 4; ++w) lse_merge(M, S, cm[w], cs[w]);
            st_sh = M + logf(S);
        }
        __syncthreads();
        const float st = st_sh;
        const int i = bid * NTHR + tid;
        if (i < V) out[i] -= st;
    }
}

extern "C" void kernel_launch(void* const* d_in, const int* in_sizes, int n_in,
                              void* d_out, int out_size, void* d_ws, size_t ws_size,
                              hipStream_t stream) {
    const int*   token = (const int*)d_in[0];
    const float* h0    = (const float*)d_in[1];
    const float* c0    = (const float*)d_in[2];
    const float* emb   = (const float*)d_in[3];
    const float* W_ih  = (const float*)d_in[4];
    const float* W_hh  = (const float*)d_in[5];
    const float* b_ih  = (const float*)d_in[6];
    const float* b_hh  = (const float*)d_in[7];
    const float* W_out = (const float*)d_in[8];
    const float* b_out = (const float*)d_in[9];
    float* out = (float*)d_out;
    float* ws  = (float*)d_ws;

    void* args[] = {
        (void*)&token, (void*)&h0, (void*)&c0, (void*)&emb,
        (void*)&W_ih, (void*)&W_hh, (void*)&b_ih, (void*)&b_hh,
        (void*)&W_out, (void*)&b_out, (void*)&out, (void*)&ws,
    };
    hipLaunchCooperativeKernel((void*)k_fused, dim3(NBLK), dim3(NTHR), args, 0, stream);
}

// Round 3
// 50.579 us; speedup vs baseline: 7.4270x; 7.4270x over previous
//
#include <hip/hip_runtime.h>
#include <cmath>

#define V 50257
#define H 1024
#define NB_LOGITS ((V + 15) / 16)      // 3142 blocks, 16 rows each
#define NB_NORM ((V + 255) / 256)      // 197 blocks

// ws layout (floats):
// [0, H)                 h1
// [H, H + 2*NB_LOGITS)   per-block (max, sumexp) partials

__device__ __forceinline__ float dot4(float4 a, float4 b) {
    return a.x * b.x + a.y * b.y + a.z * b.z + a.w * b.w;
}

__device__ __forceinline__ void lse_merge(float& m, float& s, float mo, float so) {
    const float mn = fmaxf(m, mo);
    s = s * expf(m - mn) + so * expf(mo - mn);
    m = mn;
}

// Block j computes the 4 gate dots for hidden unit j (wave w -> gate row w*H+j),
// then finishes the LSTM cell in-block. h1 -> ws, h1/c1 -> out tail.
__global__ __launch_bounds__(256) void k_gates_cell(const int* __restrict__ token,
                                                    const float* __restrict__ h0,
                                                    const float* __restrict__ c0,
                                                    const float* __restrict__ emb,
                                                    const float* __restrict__ W_ih,
                                                    const float* __restrict__ W_hh,
                                                    const float* __restrict__ b_ih,
                                                    const float* __restrict__ b_hh,
                                                    float* __restrict__ out,
                                                    float* __restrict__ h1ws) {
    const int tid = threadIdx.x;
    const int wid = tid >> 6, lane = tid & 63;
    const int j = blockIdx.x;           // hidden unit
    const int row = wid * H + j;        // gate row: wave 0..3 -> i,f,g,o
    const int tok = token[0];

    const float4* x4 = (const float4*)(emb + (size_t)tok * H);
    const float4* h4 = (const float4*)h0;
    const float4* wi = (const float4*)(W_ih + (size_t)row * H);
    const float4* wh = (const float4*)(W_hh + (size_t)row * H);

    float acc = 0.f;
#pragma unroll
    for (int it = 0; it < 4; ++it) {
        const int k4 = it * 64 + lane;
        float4 xv = x4[k4];
        xv.x = fmaxf(xv.x, 0.f); xv.y = fmaxf(xv.y, 0.f);
        xv.z = fmaxf(xv.z, 0.f); xv.w = fmaxf(xv.w, 0.f);
        acc += dot4(wi[k4], xv);
        acc += dot4(wh[k4], h4[k4]);
    }
#pragma unroll
    for (int off = 32; off; off >>= 1) acc += __shfl_down(acc, off);

    __shared__ float gsh[4];
    if (lane == 0) gsh[wid] = acc + b_ih[row] + b_hh[row];
    __syncthreads();
    if (tid == 0) {
        const float gi = gsh[0], gf = gsh[1], gg = gsh[2], go = gsh[3];
        const float si = 1.f / (1.f + expf(-gi));
        const float sf = 1.f / (1.f + expf(-gf));
        const float so = 1.f / (1.f + expf(-go));
        const float c1 = sf * c0[j] + si * tanhf(gg);
        const float h1 = so * tanhf(c1);
        out[V + j]     = h1;
        out[V + H + j] = c1;
        h1ws[j]        = h1;
    }
}

// logits[row] = dot(W_out[row], h1) + b_out[row]; 4 rows/wave, 16 rows/block.
// Emits per-block (max, sum exp(l - max)) partials.
__global__ __launch_bounds__(256) void k_logits(const float* __restrict__ h1,
                                                const float* __restrict__ W_out,
                                                const float* __restrict__ b_out,
                                                float* __restrict__ out,
                                                float* __restrict__ partials) {
    const int tid = threadIdx.x;
    const int wid = tid >> 6, lane = tid & 63;

    float4 hv[4];
    const float4* h4 = (const float4*)h1;
#pragma unroll
    for (int it = 0; it < 4; ++it) hv[it] = h4[it * 64 + lane];

    const int row0 = (blockIdx.x * 4 + wid) * 4;
    float vals[4];
#pragma unroll
    for (int r = 0; r < 4; ++r) {
        const int row = row0 + r;
        float acc = 0.f;
        if (row < V) {
            const float4* w = (const float4*)(W_out + (size_t)row * H);
#pragma unroll
            for (int it = 0; it < 4; ++it) acc += dot4(w[it * 64 + lane], hv[it]);
        }
#pragma unroll
        for (int off = 32; off; off >>= 1) acc += __shfl_down(acc, off);
        vals[r] = acc;  // valid at lane 0
    }

    __shared__ float blk[16];
    if (lane == 0) {
#pragma unroll
        for (int r = 0; r < 4; ++r) {
            const int row = row0 + r;
            if (row < V) {
                const float l = vals[r] + b_out[row];
                out[row] = l;
                blk[wid * 4 + r] = l;
            } else {
                blk[wid * 4 + r] = -INFINITY;
            }
        }
    }
    __syncthreads();
    if (tid == 0) {
        float m = -INFINITY;
        for (int i = 0; i < 16; ++i) m = fmaxf(m, blk[i]);
        float s = 0.f;
        for (int i = 0; i < 16; ++i) s += expf(blk[i] - m);
        partials[2 * blockIdx.x]     = m;
        partials[2 * blockIdx.x + 1] = s;
    }
}

// Each block redundantly merges all partials (L2-hot, 25 KB) then subtracts
// the log-sum-exp from its 256 output elements.
__global__ __launch_bounds__(256) void k_norm(const float* __restrict__ partials,
                                              float* __restrict__ out) {
    const int tid = threadIdx.x;
    const int wid = tid >> 6, lane = tid & 63;

    float m = -INFINITY, s = 0.f;
    for (int i = tid; i < NB_LOGITS; i += 256)
        lse_merge(m, s, partials[2 * i], partials[2 * i + 1]);
#pragma unroll
    for (int off = 32; off; off >>= 1) {
        const float mo = __shfl_down(m, off), so = __shfl_down(s, off);
        lse_merge(m, s, mo, so);
    }
    __shared__ float cm[4], cs[4], st_sh;
    if (lane == 0) { cm[wid] = m; cs[wid] = s; }
    __syncthreads();
    if (tid == 0) {
        float M = cm[0], S = cs[0];
#pragma unroll
        for (int w = 1; w < 4; ++w) lse_merge(M, S, cm[w], cs[w]);
        st_sh = M + logf(S);
    }
    __syncthreads();
    const float st = st_sh;
    const int i = blockIdx.x * 256 + tid;
    if (i < V) out[i] -= st;
}

extern "C" void kernel_launch(void* const* d_in, const int* in_sizes, int n_in,
                              void* d_out, int out_size, void* d_ws, size_t ws_size,
                              hipStream_t stream) {
    const int*   token = (const int*)d_in[0];
    const float* h0    = (const float*)d_in[1];
    const float* c0    = (const float*)d_in[2];
    const float* emb   = (const float*)d_in[3];
    const float* W_ih  = (const float*)d_in[4];
    const float* W_hh  = (const float*)d_in[5];
    const float* b_ih  = (const float*)d_in[6];
    const float* b_hh  = (const float*)d_in[7];
    const float* W_out = (const float*)d_in[8];
    const float* b_out = (const float*)d_in[9];

    float* out = (float*)d_out;
    float* ws  = (float*)d_ws;
    float* h1ws     = ws;
    float* partials = ws + H;

    k_gates_cell<<<H, 256, 0, stream>>>(token, h0, c0, emb, W_ih, W_hh, b_ih, b_hh, out, h1ws);
    k_logits<<<NB_LOGITS, 256, 0, stream>>>(h1ws, W_out, b_out, out, partials);
    k_norm<<<NB_NORM, 256, 0, stream>>>(partials, out);
}

// Round 4
// 47.771 us; speedup vs baseline: 7.8635x; 1.0588x over previous
//
#include <hip/hip_runtime.h>
#include <cmath>

#define V 50257
#define H 1024
#define NB_LOGITS ((V + 15) / 16)      // 3142 blocks, 16 rows each
#define NB_NORM ((V + 255) / 256)      // 197 blocks

// ws layout (floats):
// [0, H)                  h1
// [H, H + 2*NB_LOGITS)    per-block (max, sumexp) partials, as float2

__device__ __forceinline__ float dot4(float4 a, float4 b) {
    return a.x * b.x + a.y * b.y + a.z * b.z + a.w * b.w;
}

__device__ __forceinline__ void lse_merge(float& m, float& s, float mo, float so) {
    const float mn = fmaxf(m, mo);
    s = s * __expf(m - mn) + so * __expf(mo - mn);
    m = mn;
}

// Block j computes the 4 gate dots for hidden unit j (wave w -> gate row w*H+j),
// then finishes the LSTM cell in-block. h1 -> ws, h1/c1 -> out tail.
__global__ __launch_bounds__(256) void k_gates_cell(const int* __restrict__ token,
                                                    const float* __restrict__ h0,
                                                    const float* __restrict__ c0,
                                                    const float* __restrict__ emb,
                                                    const float* __restrict__ W_ih,
                                                    const float* __restrict__ W_hh,
                                                    const float* __restrict__ b_ih,
                                                    const float* __restrict__ b_hh,
                                                    float* __restrict__ out,
                                                    float* __restrict__ h1ws) {
    const int tid = threadIdx.x;
    const int wid = tid >> 6, lane = tid & 63;
    const int j = blockIdx.x;           // hidden unit
    const int row = wid * H + j;        // gate row: wave 0..3 -> i,f,g,o
    const int tok = token[0];

    const float4* x4 = (const float4*)(emb + (size_t)tok * H);
    const float4* h4 = (const float4*)h0;
    const float4* wi = (const float4*)(W_ih + (size_t)row * H);
    const float4* wh = (const float4*)(W_hh + (size_t)row * H);

    // explicit prefetch: all 16 loads in flight before any FMA
    float4 wiv[4], whv[4], xv[4], hv[4];
#pragma unroll
    for (int it = 0; it < 4; ++it) {
        const int k4 = it * 64 + lane;
        wiv[it] = wi[k4];
        whv[it] = wh[k4];
        xv[it]  = x4[k4];
        hv[it]  = h4[k4];
    }

    float acc = 0.f;
#pragma unroll
    for (int it = 0; it < 4; ++it) {
        float4 x = xv[it];
        x.x = fmaxf(x.x, 0.f); x.y = fmaxf(x.y, 0.f);
        x.z = fmaxf(x.z, 0.f); x.w = fmaxf(x.w, 0.f);
        acc += dot4(wiv[it], x);
        acc += dot4(whv[it], hv[it]);
    }
#pragma unroll
    for (int off = 32; off; off >>= 1) acc += __shfl_xor(acc, off);

    __shared__ float gsh[4];
    if (lane == 0) gsh[wid] = acc + b_ih[row] + b_hh[row];
    __syncthreads();
    if (tid == 0) {
        const float gi = gsh[0], gf = gsh[1], gg = gsh[2], go = gsh[3];
        const float si = 1.f / (1.f + __expf(-gi));
        const float sf = 1.f / (1.f + __expf(-gf));
        const float so = 1.f / (1.f + __expf(-go));
        const float c1 = sf * c0[j] + si * tanhf(gg);
        const float h1 = so * tanhf(c1);
        out[V + j]     = h1;
        out[V + H + j] = c1;
        h1ws[j]        = h1;
    }
}

// logits[row] = dot(W_out[row], h1) + b_out[row]; 4 rows/wave, 16 rows/block.
// All 16 W_out float4 fragments prefetched up-front for max MLP.
__global__ __launch_bounds__(256) void k_logits(const float* __restrict__ h1,
                                                const float* __restrict__ W_out,
                                                const float* __restrict__ b_out,
                                                float* __restrict__ out,
                                                float2* __restrict__ partials) {
    const int tid = threadIdx.x;
    const int wid = tid >> 6, lane = tid & 63;

    float4 hv[4];
    const float4* h4 = (const float4*)h1;
#pragma unroll
    for (int it = 0; it < 4; ++it) hv[it] = h4[it * 64 + lane];

    const int row0 = (blockIdx.x * 4 + wid) * 4;

    // prefetch all 16 row-fragments (clamped rows stay in-bounds; masked later)
    float4 w[4][4];
#pragma unroll
    for (int r = 0; r < 4; ++r) {
        const int rr = min(row0 + r, V - 1);
        const float4* wp = (const float4*)(W_out + (size_t)rr * H);
#pragma unroll
        for (int it = 0; it < 4; ++it) w[r][it] = wp[it * 64 + lane];
    }

    float myv = 0.f;  // lanes 0..3 end up holding rows row0..row0+3
#pragma unroll
    for (int r = 0; r < 4; ++r) {
        float acc = dot4(w[r][0], hv[0]) + dot4(w[r][1], hv[1]) +
                    dot4(w[r][2], hv[2]) + dot4(w[r][3], hv[3]);
#pragma unroll
        for (int off = 32; off; off >>= 1) acc += __shfl_xor(acc, off);
        if (lane == r) myv = acc;
    }

    __shared__ float blk[16];
    if (lane < 4) {
        const int row = row0 + lane;
        if (row < V) {
            const float l = myv + b_out[row];
            out[row] = l;
            blk[wid * 4 + lane] = l;
        } else {
            blk[wid * 4 + lane] = -INFINITY;
        }
    }
    __syncthreads();
    // parallel tail: wave 0, lanes 0..15
    if (wid == 0 && lane < 16) {
        float v = blk[lane];
        float m = v;
#pragma unroll
        for (int off = 8; off; off >>= 1) m = fmaxf(m, __shfl_xor(m, off));
        float e = __expf(v - m);
#pragma unroll
        for (int off = 8; off; off >>= 1) e += __shfl_xor(e, off);
        if (lane == 0) partials[blockIdx.x] = make_float2(m, e);
    }
}

// Each block redundantly merges all partials (L2-hot, 25 KB) then subtracts
// the log-sum-exp from its 256 output elements.
__global__ __launch_bounds__(256) void k_norm(const float2* __restrict__ partials,
                                              float* __restrict__ out) {
    const int tid = threadIdx.x;
    const int wid = tid >> 6, lane = tid & 63;

    float m = -INFINITY, s = 0.f;
    for (int i = tid; i < NB_LOGITS; i += 256) {
        const float2 p = partials[i];
        lse_merge(m, s, p.x, p.y);
    }
#pragma unroll
    for (int off = 32; off; off >>= 1) {
        const float mo = __shfl_xor(m, off), so = __shfl_xor(s, off);
        lse_merge(m, s, mo, so);
    }
    __shared__ float cm[4], cs[4], st_sh;
    if (lane == 0) { cm[wid] = m; cs[wid] = s; }
    __syncthreads();
    if (tid == 0) {
        float M = cm[0], S = cs[0];
#pragma unroll
        for (int w = 1; w < 4; ++w) lse_merge(M, S, cm[w], cs[w]);
        st_sh = M + __logf(S);
    }
    __syncthreads();
    const float st = st_sh;
    const int i = blockIdx.x * 256 + tid;
    if (i < V) out[i] -= st;
}

extern "C" void kernel_launch(void* const* d_in, const int* in_sizes, int n_in,
                              void* d_out, int out_size, void* d_ws, size_t ws_size,
                              hipStream_t stream) {
    const int*   token = (const int*)d_in[0];
    const float* h0    = (const float*)d_in[1];
    const float* c0    = (const float*)d_in[2];
    const float* emb   = (const float*)d_in[3];
    const float* W_ih  = (const float*)d_in[4];
    const float* W_hh  = (const float*)d_in[5];
    const float* b_ih  = (const float*)d_in[6];
    const float* b_hh  = (const float*)d_in[7];
    const float* W_out = (const float*)d_in[8];
    const float* b_out = (const float*)d_in[9];

    float* out = (float*)d_out;
    float* ws  = (float*)d_ws;
    float* h1ws      = ws;
    float2* partials = (float2*)(ws + H);

    k_gates_cell<<<H, 256, 0, stream>>>(token, h0, c0, emb, W_ih, W_hh, b_ih, b_hh, out, h1ws);
    k_logits<<<NB_LOGITS, 256, 0, stream>>>(h1ws, W_out, b_out, out, partials);
    k_norm<<<NB_NORM, 256, 0, stream>>>(partials, out);
}

// Round 5
// 47.734 us; speedup vs baseline: 7.8698x; 1.0008x over previous
//
#include <hip/hip_runtime.h>
#include <cmath>

#define V 50257
#define H 1024
#define NB_LOGITS ((V + 15) / 16)      // 3142 blocks, 16 rows each
#define NB_NORM ((V + 255) / 256)      // 197 blocks

// ws layout (floats):
// [0, H)                  h1
// [H, H + 2*NB_LOGITS)    per-block (max, sumexp) partials, as float2

__device__ __forceinline__ float dot4(float4 a, float4 b) {
    return a.x * b.x + a.y * b.y + a.z * b.z + a.w * b.w;
}

__device__ __forceinline__ void lse_merge(float& m, float& s, float mo, float so) {
    const float mn = fmaxf(m, mo);
    s = s * __expf(m - mn) + so * __expf(mo - mn);
    m = mn;
}

// Block j computes the 4 gate dots for hidden unit j (wave w -> gate row w*H+j),
// then finishes the LSTM cell in-block. h1 -> ws, h1/c1 -> out tail.
__global__ __launch_bounds__(256) void k_gates_cell(const int* __restrict__ token,
                                                    const float* __restrict__ h0,
                                                    const float* __restrict__ c0,
                                                    const float* __restrict__ emb,
                                                    const float* __restrict__ W_ih,
                                                    const float* __restrict__ W_hh,
                                                    const float* __restrict__ b_ih,
                                                    const float* __restrict__ b_hh,
                                                    float* __restrict__ out,
                                                    float* __restrict__ h1ws) {
    const int tid = threadIdx.x;
    const int wid = tid >> 6, lane = tid & 63;
    const int j = blockIdx.x;           // hidden unit
    const int row = wid * H + j;        // gate row: wave 0..3 -> i,f,g,o
    const int tok = token[0];

    const float4* x4 = (const float4*)(emb + (size_t)tok * H);
    const float4* h4 = (const float4*)h0;
    const float4* wi = (const float4*)(W_ih + (size_t)row * H);
    const float4* wh = (const float4*)(W_hh + (size_t)row * H);

    float4 wiv[4], whv[4], xv[4], hv[4];
#pragma unroll
    for (int it = 0; it < 4; ++it) {
        const int k4 = it * 64 + lane;
        wiv[it] = wi[k4];
        whv[it] = wh[k4];
        xv[it]  = x4[k4];
        hv[it]  = h4[k4];
    }

    float acc = 0.f;
#pragma unroll
    for (int it = 0; it < 4; ++it) {
        float4 x = xv[it];
        x.x = fmaxf(x.x, 0.f); x.y = fmaxf(x.y, 0.f);
        x.z = fmaxf(x.z, 0.f); x.w = fmaxf(x.w, 0.f);
        acc += dot4(wiv[it], x);
        acc += dot4(whv[it], hv[it]);
    }
#pragma unroll
    for (int off = 32; off; off >>= 1) acc += __shfl_xor(acc, off);

    __shared__ float gsh[4];
    if (lane == 0) gsh[wid] = acc + b_ih[row] + b_hh[row];
    __syncthreads();
    if (tid == 0) {
        const float gi = gsh[0], gf = gsh[1], gg = gsh[2], go = gsh[3];
        const float si = 1.f / (1.f + __expf(-gi));
        const float sf = 1.f / (1.f + __expf(-gf));
        const float so = 1.f / (1.f + __expf(-go));
        const float c1 = sf * c0[j] + si * tanhf(gg);
        const float h1 = so * tanhf(c1);
        out[V + j]     = h1;
        out[V + H + j] = c1;
        h1ws[j]        = h1;
    }
}

// logits[row] = dot(W_out[row], h1) + b_out[row]; 4 rows/wave, 16 rows/block.
// Cross-lane reduction via LDS transpose (9 DS-ish ops/thread vs 24 shfl).
__global__ __launch_bounds__(256) void k_logits(const float* __restrict__ h1,
                                                const float* __restrict__ W_out,
                                                const float* __restrict__ b_out,
                                                float* __restrict__ out,
                                                float2* __restrict__ partials) {
    const int tid = threadIdx.x;
    const int wid = tid >> 6, lane = tid & 63;

    __shared__ float arr[16 * 64];   // [local row][lane] partials
    __shared__ float blk[16];

    float4 hv[4];
    const float4* h4 = (const float4*)h1;
#pragma unroll
    for (int it = 0; it < 4; ++it) hv[it] = h4[it * 64 + lane];

    const int row0 = blockIdx.x * 16;
    const int wrow0 = row0 + wid * 4;

    // prefetch all 16 row-fragments (clamped rows stay in-bounds; masked later)
    float4 w[4][4];
#pragma unroll
    for (int r = 0; r < 4; ++r) {
        const int rr = min(wrow0 + r, V - 1);
        const float4* wp = (const float4*)(W_out + (size_t)rr * H);
#pragma unroll
        for (int it = 0; it < 4; ++it) w[r][it] = wp[it * 64 + lane];
    }

    // 4 independent per-lane row partials
#pragma unroll
    for (int r = 0; r < 4; ++r) {
        const float acc = dot4(w[r][0], hv[0]) + dot4(w[r][1], hv[1]) +
                          dot4(w[r][2], hv[2]) + dot4(w[r][3], hv[3]);
        arr[(wid * 4 + r) * 64 + lane] = acc;
    }
    __syncthreads();

    // transpose reduce: group g (16 lanes) sums local row g's 64 partials
    {
        const int g = tid >> 4, i = tid & 15;
        const float4 p = ((const float4*)arr)[g * 16 + i];
        float v = (p.x + p.y) + (p.z + p.w);
#pragma unroll
        for (int off = 8; off; off >>= 1) v += __shfl_xor(v, off);
        if (i == 0) {
            const int row = row0 + g;
            if (row < V) {
                const float l = v + b_out[row];
                out[row] = l;
                blk[g] = l;
            } else {
                blk[g] = -INFINITY;
            }
        }
    }
    __syncthreads();

    // parallel tail: wave 0, lanes 0..15 -> per-block (max, sumexp)
    if (wid == 0 && lane < 16) {
        float v = blk[lane];
        float m = v;
#pragma unroll
        for (int off = 8; off; off >>= 1) m = fmaxf(m, __shfl_xor(m, off));
        float e = __expf(v - m);
#pragma unroll
        for (int off = 8; off; off >>= 1) e += __shfl_xor(e, off);
        if (lane == 0) partials[blockIdx.x] = make_float2(m, e);
    }
}

// Each block redundantly merges all partials (L2-hot, 25 KB) then subtracts
// the log-sum-exp from its 256 output elements.
__global__ __launch_bounds__(256) void k_norm(const float2* __restrict__ partials,
                                              float* __restrict__ out) {
    const int tid = threadIdx.x;
    const int wid = tid >> 6, lane = tid & 63;

    float m = -INFINITY, s = 0.f;
    for (int i = tid; i < NB_LOGITS; i += 256) {
        const float2 p = partials[i];
        lse_merge(m, s, p.x, p.y);
    }
#pragma unroll
    for (int off = 32; off; off >>= 1) {
        const float mo = __shfl_xor(m, off), so = __shfl_xor(s, off);
        lse_merge(m, s, mo, so);
    }
    __shared__ float cm[4], cs[4], st_sh;
    if (lane == 0) { cm[wid] = m; cs[wid] = s; }
    __syncthreads();
    if (tid == 0) {
        float M = cm[0], S = cs[0];
#pragma unroll
        for (int w = 1; w < 4; ++w) lse_merge(M, S, cm[w], cs[w]);
        st_sh = M + __logf(S);
    }
    __syncthreads();
    const float st = st_sh;
    const int i = blockIdx.x * 256 + tid;
    if (i < V) out[i] -= st;
}

extern "C" void kernel_launch(void* const* d_in, const int* in_sizes, int n_in,
                              void* d_out, int out_size, void* d_ws, size_t ws_size,
                              hipStream_t stream) {
    const int*   token = (const int*)d_in[0];
    const float* h0    = (const float*)d_in[1];
    const float* c0    = (const float*)d_in[2];
    const float* emb   = (const float*)d_in[3];
    const float* W_ih  = (const float*)d_in[4];
    const float* W_hh  = (const float*)d_in[5];
    const float* b_ih  = (const float*)d_in[6];
    const float* b_hh  = (const float*)d_in[7];
    const float* W_out = (const float*)d_in[8];
    const float* b_out = (const float*)d_in[9];

    float* out = (float*)d_out;
    float* ws  = (float*)d_ws;
    float* h1ws      = ws;
    float2* partials = (float2*)(ws + H);

    k_gates_cell<<<H, 256, 0, stream>>>(token, h0, c0, emb, W_ih, W_hh, b_ih, b_hh, out, h1ws);
    k_logits<<<NB_LOGITS, 256, 0, stream>>>(h1ws, W_out, b_out, out, partials);
    k_norm<<<NB_NORM, 256, 0, stream>>>(partials, out);
}